// Round 1
// baseline (311.712 us; speedup 1.0000x reference)
//
#include <hip/hip_runtime.h>

// out[s, j] = dot(z[s,:], W[c[s]*12288 + j, :]) + b[c[s]*12288 + j]
// z: [1024,128] f32, c: [1024] int, W: [196608,128] f32, b: [196608] f32
// out: [1024, 12288] f32   (12288 = 3*64*64 features per expert)

#define Z_DIM 128
#define OUT_PER_EXPERT 12288
#define N_EXPERTS 16
#define NT 128          // threads per block == output columns per block
#define MU 4            // samples processed per inner iteration
#define MAX_B 1024

__global__ __launch_bounds__(NT, 3)
void expert_gemm(const float* __restrict__ z,
                 const int* __restrict__ c,
                 const float* __restrict__ W,
                 const float* __restrict__ bias,
                 float* __restrict__ out,
                 int B) {
    const int e = blockIdx.y;

    // --- Build this expert's sample list in LDS (order irrelevant) ---
    __shared__ int lst[MAX_B];
    __shared__ int cnt_sh;
    if (threadIdx.x == 0) cnt_sh = 0;
    __syncthreads();
    for (int i = threadIdx.x; i < B; i += NT) {
        if (c[i] == e) {
            int p = atomicAdd(&cnt_sh, 1);
            lst[p] = i;
        }
    }
    __syncthreads();
    const int cnt = cnt_sh;
    if (cnt == 0) return;   // expert 15 (and any unused expert): no W read at all

    // --- Each thread owns one W row (stationary in 128 VGPRs) ---
    const int n = blockIdx.x * NT + threadIdx.x;
    const long long row = (long long)e * OUT_PER_EXPERT + n;

    float w[Z_DIM];
    {
        const float4* wp = (const float4*)(W + row * Z_DIM);
        #pragma unroll
        for (int k4 = 0; k4 < Z_DIM / 4; ++k4)
            ((float4*)w)[k4] = wp[k4];
    }
    const float bv = bias[row];

    // --- Stream samples, 4 at a time; z addresses are wave-uniform ---
    for (int m0 = 0; m0 < cnt; m0 += MU) {
        const int i1 = min(m0 + 1, cnt - 1);
        const int i2 = min(m0 + 2, cnt - 1);
        const int i3 = min(m0 + 3, cnt - 1);
        const int s0 = __builtin_amdgcn_readfirstlane(lst[m0]);
        const int s1 = __builtin_amdgcn_readfirstlane(lst[i1]);
        const int s2 = __builtin_amdgcn_readfirstlane(lst[i2]);
        const int s3 = __builtin_amdgcn_readfirstlane(lst[i3]);

        const float4* z0 = (const float4*)(z + (size_t)s0 * Z_DIM);
        const float4* z1 = (const float4*)(z + (size_t)s1 * Z_DIM);
        const float4* z2 = (const float4*)(z + (size_t)s2 * Z_DIM);
        const float4* z3 = (const float4*)(z + (size_t)s3 * Z_DIM);

        float a0 = bv, a1 = bv, a2 = bv, a3 = bv;
        #pragma unroll
        for (int k4 = 0; k4 < Z_DIM / 4; ++k4) {
            const float w0 = w[4 * k4 + 0];
            const float w1 = w[4 * k4 + 1];
            const float w2 = w[4 * k4 + 2];
            const float w3 = w[4 * k4 + 3];
            const float4 v0 = z0[k4];
            const float4 v1 = z1[k4];
            const float4 v2 = z2[k4];
            const float4 v3 = z3[k4];
            a0 = fmaf(v0.x, w0, a0); a0 = fmaf(v0.y, w1, a0);
            a0 = fmaf(v0.z, w2, a0); a0 = fmaf(v0.w, w3, a0);
            a1 = fmaf(v1.x, w0, a1); a1 = fmaf(v1.y, w1, a1);
            a1 = fmaf(v1.z, w2, a1); a1 = fmaf(v1.w, w3, a1);
            a2 = fmaf(v2.x, w0, a2); a2 = fmaf(v2.y, w1, a2);
            a2 = fmaf(v2.z, w2, a2); a2 = fmaf(v2.w, w3, a2);
            a3 = fmaf(v3.x, w0, a3); a3 = fmaf(v3.y, w1, a3);
            a3 = fmaf(v3.z, w2, a3); a3 = fmaf(v3.w, w3, a3);
        }

        out[(size_t)s0 * OUT_PER_EXPERT + n] = a0;
        if (m0 + 1 < cnt) out[(size_t)s1 * OUT_PER_EXPERT + n] = a1;
        if (m0 + 2 < cnt) out[(size_t)s2 * OUT_PER_EXPERT + n] = a2;
        if (m0 + 3 < cnt) out[(size_t)s3 * OUT_PER_EXPERT + n] = a3;
    }
}

extern "C" void kernel_launch(void* const* d_in, const int* in_sizes, int n_in,
                              void* d_out, int out_size, void* d_ws, size_t ws_size,
                              hipStream_t stream) {
    const float* z = (const float*)d_in[0];
    const int*   c = (const int*)d_in[1];
    const float* W = (const float*)d_in[2];
    const float* b = (const float*)d_in[3];
    float* out = (float*)d_out;
    const int B = in_sizes[0] / Z_DIM;   // 1024

    dim3 grid(OUT_PER_EXPERT / NT, N_EXPERTS);
    expert_gemm<<<grid, NT, 0, stream>>>(z, c, W, b, out, B);
}

// Round 4
// 310.205 us; speedup vs baseline: 1.0049x; 1.0049x over previous
//
#include <hip/hip_runtime.h>

// out[s, j] = dot(z[s,:], W[c[s]*12288 + j, :]) + b[c[s]*12288 + j]
// z: [1024,128] f32, c: [1024] int, W: [196608,128] f32, b: [196608] f32
// out: [1024, 12288] f32   (12288 = 3*64*64 features per expert)
//
// W-stationary grouped mat-vec: block = (expert, 128-col tile); each thread
// owns ONE W row in 128 VGPRs (float4 w4[32] — no alias casts, so SROA keeps
// it in registers), streams the expert's samples 4 at a time with
// wave-uniform (scalar-cache) z loads.

#define Z_DIM 128
#define OUT_PER_EXPERT 12288
#define N_EXPERTS 16
#define NT 128
#define MU 4
#define MAX_B 1024

__global__ __launch_bounds__(NT, 3)
void expert_gemm(const float* __restrict__ z,
                 const int* __restrict__ c,
                 const float* __restrict__ W,
                 const float* __restrict__ bias,
                 float* __restrict__ out,
                 int B) {
    const int e = blockIdx.y;

    // --- Build this expert's sample list in LDS ---
    __shared__ int lst[MAX_B];
    __shared__ int cnt_sh;
    if (threadIdx.x == 0) cnt_sh = 0;
    __syncthreads();
    for (int i = threadIdx.x; i < B; i += NT) {
        if (c[i] == e) {
            int p = atomicAdd(&cnt_sh, 1);
            lst[p] = i;
        }
    }
    __syncthreads();
    const int cnt = cnt_sh;
    if (cnt == 0) return;   // expert 15: untouched, no W read

    const int n = blockIdx.x * NT + threadIdx.x;
    const long long row = (long long)e * OUT_PER_EXPERT + n;

    // --- W row stationary in VGPRs: direct float4 array, constant indices ---
    float4 w4[Z_DIM / 4];
    {
        const float4* wp = (const float4*)(W + row * Z_DIM);
        #pragma unroll
        for (int k4 = 0; k4 < Z_DIM / 4; ++k4)
            w4[k4] = wp[k4];
    }
    const float bv = bias[row];

    for (int m0 = 0; m0 < cnt; m0 += MU) {
        const int i1 = min(m0 + 1, cnt - 1);
        const int i2 = min(m0 + 2, cnt - 1);
        const int i3 = min(m0 + 3, cnt - 1);
        // wave-uniform sample ids -> scalar z loads through K$
        const int s0 = __builtin_amdgcn_readfirstlane(lst[m0]);
        const int s1 = __builtin_amdgcn_readfirstlane(lst[i1]);
        const int s2 = __builtin_amdgcn_readfirstlane(lst[i2]);
        const int s3 = __builtin_amdgcn_readfirstlane(lst[i3]);

        const float4* z0 = (const float4*)(z + (size_t)s0 * Z_DIM);
        const float4* z1 = (const float4*)(z + (size_t)s1 * Z_DIM);
        const float4* z2 = (const float4*)(z + (size_t)s2 * Z_DIM);
        const float4* z3 = (const float4*)(z + (size_t)s3 * Z_DIM);

        float a0 = bv, a1 = bv, a2 = bv, a3 = bv;
        #pragma unroll
        for (int k4 = 0; k4 < Z_DIM / 4; ++k4) {
            const float4 wv = w4[k4];
            const float4 v0 = z0[k4];
            const float4 v1 = z1[k4];
            const float4 v2 = z2[k4];
            const float4 v3 = z3[k4];
            a0 = fmaf(v0.x, wv.x, a0); a0 = fmaf(v0.y, wv.y, a0);
            a0 = fmaf(v0.z, wv.z, a0); a0 = fmaf(v0.w, wv.w, a0);
            a1 = fmaf(v1.x, wv.x, a1); a1 = fmaf(v1.y, wv.y, a1);
            a1 = fmaf(v1.z, wv.z, a1); a1 = fmaf(v1.w, wv.w, a1);
            a2 = fmaf(v2.x, wv.x, a2); a2 = fmaf(v2.y, wv.y, a2);
            a2 = fmaf(v2.z, wv.z, a2); a2 = fmaf(v2.w, wv.w, a2);
            a3 = fmaf(v3.x, wv.x, a3); a3 = fmaf(v3.y, wv.y, a3);
            a3 = fmaf(v3.z, wv.z, a3); a3 = fmaf(v3.w, wv.w, a3);
        }

        out[(size_t)s0 * OUT_PER_EXPERT + n] = a0;
        if (m0 + 1 < cnt) out[(size_t)s1 * OUT_PER_EXPERT + n] = a1;
        if (m0 + 2 < cnt) out[(size_t)s2 * OUT_PER_EXPERT + n] = a2;
        if (m0 + 3 < cnt) out[(size_t)s3 * OUT_PER_EXPERT + n] = a3;
    }
}

extern "C" void kernel_launch(void* const* d_in, const int* in_sizes, int n_in,
                              void* d_out, int out_size, void* d_ws, size_t ws_size,
                              hipStream_t stream) {
    const float* z = (const float*)d_in[0];
    const int*   c = (const int*)d_in[1];
    const float* W = (const float*)d_in[2];
    const float* b = (const float*)d_in[3];
    float* out = (float*)d_out;
    const int B = in_sizes[0] / Z_DIM;   // 1024

    dim3 grid(OUT_PER_EXPERT / NT, N_EXPERTS);
    expert_gemm<<<grid, NT, 0, stream>>>(z, c, W, b, out, B);
}